// Round 10
// baseline (75.621 us; speedup 1.0000x reference)
//
#include <hip/hip_runtime.h>
#include <stdint.h>

typedef __attribute__((ext_vector_type(8))) short short8;
typedef __attribute__((ext_vector_type(8))) signed char schar8;
typedef __attribute__((ext_vector_type(4))) float f32x4;

__device__ __forceinline__ unsigned short f2bf(float f) {
  union { float f; uint32_t u; } v; v.f = f;
  uint32_t u = v.u;
  uint32_t r = (u + 0x7FFFu + ((u >> 16) & 1u)) >> 16;
  return (unsigned short)r;
}
__device__ __forceinline__ float bf2f(unsigned short h) {
  union { uint32_t u; float f; } v; v.u = ((uint32_t)h) << 16; return v.f;
}

// ============================================================================
// Phase 1: h_u[i] = src_emb[i] @ W1[:128] + b1 ; h_v[j] = dst_emb[j] @ W1[128:]
// int8 per-row quantization. ROW-WISE wave split: wave w owns rows
// [w*16,w*16+16) x all 128 cols, so per-row absmax is wave-local (no cross-
// wave LDS exchange, 2 barriers/tile). W1^T lives in LDS (bf16, XOR-swizzle).
// Logical MFMA col n -> physical col n*8+cf  =>  each lane's 8 C values are
// contiguous bytes [node*128 + l15*8 .. +8) -> single 8B coalesced store,
// channel order identical to edge phase's l15*8+j.
// ============================================================================
#define NBM 64
__global__ __launch_bounds__(256, 3)
void node_phase_q8(const float* __restrict__ src_emb,
                   const float* __restrict__ dst_emb,
                   const float* __restrict__ W1,
                   const float* __restrict__ b1,
                   int8_t* __restrict__ Q,
                   float* __restrict__ SC,
                   int Nn, int ntiles) {
  __shared__ __align__(16) char Als[NBM * 256];     // 16 KB A tile (64 x 128 bf16)
  __shared__ __align__(16) char Wlds[128 * 256];    // 32 KB W1^T: [col][k] bf16

  const int tbl = blockIdx.y;
  const float* emb = tbl ? dst_emb : src_emb;
  const float* Wt  = W1 + (size_t)tbl * 128 * 128;
  int8_t* Qt  = Q  + (size_t)tbl * Nn * 128;
  float*  SCt = SC + (size_t)tbl * Nn;

  const int tid  = threadIdx.x;
  const int lane = tid & 63;
  const int w    = tid >> 6;           // wave w -> rows [w*16, w*16+16)
  const int l15  = lane & 15;
  const int lg   = lane >> 4;          // 0..3

  // ---- W1^T -> LDS once per block. Wlds[col][k] @ ((col*256+k*2) ^ swz(col)),
  //      swz(col) = ((col>>3)&7)<<4. 2048 short8 chunks over 256 threads.
  for (int c = tid; c < 2048; c += 256) {
    const int col = c >> 4;
    const int k8  = (c & 15) * 8;
    short8 t;
#pragma unroll
    for (int j = 0; j < 8; ++j)
      t[j] = (short)f2bf(Wt[(size_t)(k8 + j) * 128 + col]);
    const int byteoff = (col * 256 + k8 * 2) ^ (((col >> 3) & 7) << 4);
    *(short8*)(Wlds + byteoff) = t;
  }

  // bias per (lane, cf): physical col = l15*8 + cf (V table has no bias)
  float b1s[8];
#pragma unroll
  for (int j = 0; j < 8; ++j) b1s[j] = tbl ? 0.f : b1[l15 * 8 + j];

  const int q = tid & 15, r0 = tid >> 4;
  const int swzA = (l15 & 7) << 4;
  const int gx = gridDim.x;

  // ---- prefetch first tile into registers ----
  float4 p0[4], p1[4];
#pragma unroll
  for (int i = 0; i < 4; ++i) {
    const int node = blockIdx.x * NBM + i * 16 + r0;
    if (node < Nn) {
      const float* base = emb + (size_t)node * 128 + q * 8;
      p0[i] = *(const float4*)base;
      p1[i] = *(const float4*)(base + 4);
    }
  }

  for (int t = blockIdx.x; t < ntiles; t += gx) {
    const int t0 = t * NBM;

    // ---- prefetched regs -> swizzled LDS ----
#pragma unroll
    for (int i = 0; i < 4; ++i) {
      const int row = i * 16 + r0;
      short8 hv;
      hv[0] = (short)f2bf(p0[i].x); hv[1] = (short)f2bf(p0[i].y);
      hv[2] = (short)f2bf(p0[i].z); hv[3] = (short)f2bf(p0[i].w);
      hv[4] = (short)f2bf(p1[i].x); hv[5] = (short)f2bf(p1[i].y);
      hv[6] = (short)f2bf(p1[i].z); hv[7] = (short)f2bf(p1[i].w);
      const int byteoff = row * 256 + ((q * 16) ^ ((row & 7) << 4));
      *(short8*)(Als + byteoff) = hv;
    }
    __syncthreads();   // also orders Wlds init before first read

    // ---- issue next tile's gathers (hide under compute) ----
    const int tn = t + gx;
    if (tn < ntiles) {
#pragma unroll
      for (int i = 0; i < 4; ++i) {
        const int node = tn * NBM + i * 16 + r0;
        if (node < Nn) {
          const float* base = emb + (size_t)node * 128 + q * 8;
          p0[i] = *(const float4*)base;
          p1[i] = *(const float4*)(base + 4);
        }
      }
    }

    // ---- MFMA: wave w computes rows w*16..+16, all 128 phys cols ----
    f32x4 acc[8];
#pragma unroll
    for (int cf = 0; cf < 8; ++cf) acc[cf] = (f32x4){0.f, 0.f, 0.f, 0.f};

#pragma unroll
    for (int s = 0; s < 4; ++s) {
      const int aoff = (w * 16 + l15) * 256 + ((s * 64 + lg * 16) ^ swzA);
      const short8 a = *(const short8*)(Als + aoff);
#pragma unroll
      for (int cf = 0; cf < 8; ++cf) {
        const int col = l15 * 8 + cf;
        const int boff = (col * 256 + s * 64 + lg * 16) ^ (((col >> 3) & 7) << 4);
        const short8 b = *(const short8*)(Wlds + boff);
        acc[cf] = __builtin_amdgcn_mfma_f32_16x16x32_bf16(a, b, acc[cf], 0, 0, 0);
      }
    }

    // ---- wave-local per-row absmax -> quantize -> 8B coalesced store ----
#pragma unroll
    for (int reg = 0; reg < 4; ++reg) {
      float h[8];
      float am = 1e-20f;
#pragma unroll
      for (int cf = 0; cf < 8; ++cf) {
        h[cf] = acc[cf][reg] + b1s[cf];
        am = fmaxf(am, fabsf(h[cf]));
      }
      am = fmaxf(am, __shfl_xor(am, 1, 16));
      am = fmaxf(am, __shfl_xor(am, 2, 16));
      am = fmaxf(am, __shfl_xor(am, 4, 16));
      am = fmaxf(am, __shfl_xor(am, 8, 16));
      const int node = t0 + w * 16 + lg * 4 + reg;
      if (node < Nn) {
        const float rq = 127.0f / am;
        uint32_t lo = 0, hi = 0;
#pragma unroll
        for (int cf = 0; cf < 4; ++cf)
          lo |= ((uint32_t)((int)rintf(h[cf] * rq) & 255)) << (8 * cf);
#pragma unroll
        for (int cf = 4; cf < 8; ++cf)
          hi |= ((uint32_t)((int)rintf(h[cf] * rq) & 255)) << (8 * (cf - 4));
        uint2 pk; pk.x = lo; pk.y = hi;
        *(uint2*)(Qt + (size_t)node * 128 + l15 * 8) = pk;
        if (l15 == 0) SCt[node] = am * (1.0f / 127.0f);
      }
    }
    __syncthreads();
  }
}

// ============================================================================
// Phase 2 (unchanged from passing R9): 16 lanes/edge, 8 int8 channels/lane.
// out[e] = sigmoid( sum_c relu(su*qu[c] + sv*qv[c]) * W2[c] + b2 )
// ============================================================================
__global__ __launch_bounds__(256, 8)
void edge_phase_q8(const int8_t* __restrict__ Qu,
                   const int8_t* __restrict__ Qv,
                   const float* __restrict__ scu,
                   const float* __restrict__ scv,
                   const int* __restrict__ eidx,
                   const float* __restrict__ W2,
                   const float* __restrict__ b2,
                   float* __restrict__ out,
                   int E) {
  const int tid = threadIdx.x;
  const int l15 = tid & 15;
  const int sg  = tid >> 4;

  float w2s[8];
#pragma unroll
  for (int j = 0; j < 8; ++j) w2s[j] = W2[l15 * 8 + j];
  const float b2s = b2[0];
  const int stride = gridDim.x * 16;

#pragma unroll 2
  for (int e = blockIdx.x * 16 + sg; e < E; e += stride) {
    const int s = eidx[e];
    const int d = eidx[E + e];
    const schar8 qu = *(const schar8*)(Qu + (size_t)s * 128 + l15 * 8);
    const schar8 qv = *(const schar8*)(Qv + (size_t)d * 128 + l15 * 8);
    const float su = scu[s];
    const float sv = scv[d];
    float acc = 0.f;
#pragma unroll
    for (int j = 0; j < 8; ++j) {
      float g = (float)(int)qu[j] * su + (float)(int)qv[j] * sv;
      g = g > 0.f ? g : 0.f;
      acc = fmaf(g, w2s[j], acc);
    }
    acc += __shfl_xor(acc, 1, 16);
    acc += __shfl_xor(acc, 2, 16);
    acc += __shfl_xor(acc, 4, 16);
    acc += __shfl_xor(acc, 8, 16);
    if (l15 == 0) out[e] = 1.f / (1.f + __expf(-(acc + b2s)));
  }
}

// ============================================================================
// Fallback (proven R2 kernel): fused gather+MFMA, used if ws_size too small.
// ============================================================================
#define BM 64
__global__ __launch_bounds__(256, 4)
void edge_decoder_fused(const float* __restrict__ src_emb,
                        const float* __restrict__ dst_emb,
                        const int* __restrict__ eidx,
                        const float* __restrict__ W1,
                        const float* __restrict__ b1,
                        const float* __restrict__ W2,
                        const float* __restrict__ b2,
                        float* __restrict__ out,
                        int E, int ntiles) {
  __shared__ __align__(16) char Als[BM * 512];
  __shared__ float rowpart[4][BM];

  const int tid  = threadIdx.x;
  const int lane = tid & 63;
  const int w    = tid >> 6;
  const int l15  = lane & 15;
  const int lk8  = (lane >> 4) * 8;

  short8 bfrag[8][2];
#pragma unroll
  for (int s = 0; s < 8; ++s) {
#pragma unroll
    for (int nf = 0; nf < 2; ++nf) {
      const int col = w * 32 + nf * 16 + l15;
      short8 t;
#pragma unroll
      for (int j = 0; j < 8; ++j) {
        const int k = s * 32 + lk8 + j;
        t[j] = (short)f2bf(W1[k * 128 + col]);
      }
      bfrag[s][nf] = t;
    }
  }
  float b1v[2], w2v[2];
#pragma unroll
  for (int nf = 0; nf < 2; ++nf) {
    const int col = w * 32 + nf * 16 + l15;
    b1v[nf] = b1[col];
    w2v[nf] = W2[col];
  }
  const float b2s = b2[0];

  const int q  = tid & 31;
  const int r0 = tid >> 5;
  const int qq = q & 15;
  const bool is_src = (q < 16);
  const int swz = (l15 & 7) << 4;

  for (int t = blockIdx.x; t < ntiles; t += gridDim.x) {
    const int t0 = t * BM;
#pragma unroll
    for (int i = 0; i < 8; ++i) {
      const int row = i * 8 + r0;
      const int e = t0 + row;
      if (e < E) {
        const int node = is_src ? eidx[e] : eidx[E + e];
        const float* base = (is_src ? src_emb : dst_emb) + (size_t)node * 128 + qq * 8;
        const float4 f0 = *(const float4*)base;
        const float4 f1 = *(const float4*)(base + 4);
        short8 hv;
        hv[0] = (short)f2bf(f0.x); hv[1] = (short)f2bf(f0.y);
        hv[2] = (short)f2bf(f0.z); hv[3] = (short)f2bf(f0.w);
        hv[4] = (short)f2bf(f1.x); hv[5] = (short)f2bf(f1.y);
        hv[6] = (short)f2bf(f1.z); hv[7] = (short)f2bf(f1.w);
        const int byteoff = row * 512 + ((q * 16) ^ ((row & 7) << 4));
        *(short8*)(Als + byteoff) = hv;
      }
    }
    __syncthreads();

    for (int m = 0; m < 4; ++m) {
      f32x4 acc0 = {0.f, 0.f, 0.f, 0.f};
      f32x4 acc1 = {0.f, 0.f, 0.f, 0.f};
      const int rowb = (m * 16 + l15) * 512;
      const int kb0  = lk8 * 2;
#pragma unroll
      for (int s = 0; s < 8; ++s) {
        const int off = rowb + ((s * 64 + kb0) ^ swz);
        const short8 a = *(const short8*)(Als + off);
        acc0 = __builtin_amdgcn_mfma_f32_16x16x32_bf16(a, bfrag[s][0], acc0, 0, 0, 0);
        acc1 = __builtin_amdgcn_mfma_f32_16x16x32_bf16(a, bfrag[s][1], acc1, 0, 0, 0);
      }
      float pr[4];
#pragma unroll
      for (int reg = 0; reg < 4; ++reg) {
        float h0 = acc0[reg] + b1v[0]; h0 = h0 > 0.f ? h0 : 0.f;
        float h1 = acc1[reg] + b1v[1]; h1 = h1 > 0.f ? h1 : 0.f;
        pr[reg] = h0 * w2v[0] + h1 * w2v[1];
      }
#pragma unroll
      for (int off = 1; off < 16; off <<= 1) {
#pragma unroll
        for (int reg = 0; reg < 4; ++reg)
          pr[reg] += __shfl_xor(pr[reg], off, 64);
      }
      if (l15 == 0) {
        const int rbase = m * 16 + (lane >> 4) * 4;
#pragma unroll
        for (int reg = 0; reg < 4; ++reg)
          rowpart[w][rbase + reg] = pr[reg];
      }
    }
    __syncthreads();

    if (tid < BM) {
      const int e = t0 + tid;
      if (e < E) {
        const float sum = rowpart[0][tid] + rowpart[1][tid] +
                          rowpart[2][tid] + rowpart[3][tid] + b2s;
        out[e] = 1.f / (1.f + __expf(-sum));
      }
    }
    __syncthreads();
  }
}

extern "C" void kernel_launch(void* const* d_in, const int* in_sizes, int n_in,
                              void* d_out, int out_size, void* d_ws, size_t ws_size,
                              hipStream_t stream) {
  const float* src = (const float*)d_in[0];
  const float* dst = (const float*)d_in[1];
  const int*   eix = (const int*)d_in[2];
  const float* W1  = (const float*)d_in[3];
  const float* b1  = (const float*)d_in[4];
  const float* W2  = (const float*)d_in[5];
  const float* b2  = (const float*)d_in[6];
  float* out = (float*)d_out;

  const int E  = in_sizes[2] / 2;
  const int Nn = in_sizes[0] / 128;
  // ws layout: Q (2 tables x Nn x 128 int8) | SC (2 tables x Nn f32)
  const size_t q_bytes  = (size_t)2 * Nn * 128;
  const size_t sc_bytes = (size_t)2 * Nn * sizeof(float);

  if (ws_size >= q_bytes + sc_bytes) {
    int8_t* Q  = (int8_t*)d_ws;
    float*  SC = (float*)((char*)d_ws + q_bytes);
    const int ntiles_n = (Nn + NBM - 1) / NBM;
    const int gx = ntiles_n < 384 ? ntiles_n : 384;   // 768 blocks = 3/CU (LDS-limited)
    node_phase_q8<<<dim3(gx, 2), 256, 0, stream>>>(src, dst, W1, b1, Q, SC, Nn, ntiles_n);
    const int nchunks = (E + 15) / 16;
    const int nblk = nchunks < 2048 ? nchunks : 2048;
    edge_phase_q8<<<nblk, 256, 0, stream>>>(Q, Q + (size_t)Nn * 128, SC, SC + Nn,
                                            eix, W2, b2, out, E);
  } else {
    const int ntiles = (E + BM - 1) / BM;
    const int grid = ntiles < 2048 ? ntiles : 2048;
    edge_decoder_fused<<<grid, 256, 0, stream>>>(src, dst, eix, W1, b1, W2, b2,
                                                 out, E, ntiles);
  }
}